// Round 2
// baseline (6071.133 us; speedup 1.0000x reference)
//
#include <hip/hip_runtime.h>
#include <math.h>

#define NODE_D 64   // hidden/output width (all layers output 64)

// ---------------- norm precompute ----------------

__global__ void k_init_deg(float* __restrict__ deg, int n) {
    int i = blockIdx.x * blockDim.x + threadIdx.x;
    if (i < n) deg[i] = 1.0f;   // self-loop contribution
}

__global__ void k_accum_deg(const int* __restrict__ dst, float* __restrict__ deg, int E) {
    int e = blockIdx.x * blockDim.x + threadIdx.x;
    if (e < E) unsafeAtomicAdd(&deg[dst[e]], 1.0f);
}

__global__ void k_dinv(float* __restrict__ deg, int n) {
    int i = blockIdx.x * blockDim.x + threadIdx.x;
    if (i < n) {
        float d = deg[i];
        deg[i] = (d > 0.0f) ? rsqrtf(d) : 0.0f;   // in-place: deg -> dinv
    }
}

__global__ void k_coef(const int* __restrict__ src, const int* __restrict__ dst,
                       const float* __restrict__ dinv, float* __restrict__ coef, int E) {
    int e = blockIdx.x * blockDim.x + threadIdx.x;
    if (e < E) coef[e] = dinv[src[e]] * dinv[dst[e]];
}

// ---------------- dense h @ W  (K = 128 or 64, out width 64) ----------------
// Block = 256 threads = 4 rows x 64 cols. Lane j owns output col j; the x-row
// element load is wave-uniform (HW broadcast), W loads are 256B coalesced.
template <int K>
__global__ void k_gemm(const float* __restrict__ h, const float* __restrict__ W,
                       float* __restrict__ xw, int n) {
    const int j   = threadIdx.x & 63;
    const int row = blockIdx.x * 4 + (threadIdx.x >> 6);
    if (row >= n) return;
    const float* hp = h + (size_t)row * K;
    float acc = 0.0f;
#pragma unroll
    for (int k = 0; k < K; k += 4) {
        float4 xv = *reinterpret_cast<const float4*>(hp + k);
        acc = fmaf(xv.x, W[(k + 0) * NODE_D + j], acc);
        acc = fmaf(xv.y, W[(k + 1) * NODE_D + j], acc);
        acc = fmaf(xv.z, W[(k + 2) * NODE_D + j], acc);
        acc = fmaf(xv.w, W[(k + 3) * NODE_D + j], acc);
    }
    xw[(size_t)row * NODE_D + j] = acc;
}

// ---------------- agg init: bias + self-loop (coef = dinv[i]^2) ----------------
__global__ void k_init_agg(const float* __restrict__ xw, const float* __restrict__ dinv,
                           const float* __restrict__ b, float* __restrict__ agg, int n) {
    int t = blockIdx.x * blockDim.x + threadIdx.x;     // one float4 per thread
    if (t >= n * 16) return;
    int row = t >> 4, c = t & 15;
    float di = dinv[row];
    float s  = di * di;
    float4 xv = reinterpret_cast<const float4*>(xw)[t];
    float4 bv = reinterpret_cast<const float4*>(b)[c];
    float4 o;
    o.x = fmaf(xv.x, s, bv.x);
    o.y = fmaf(xv.y, s, bv.y);
    o.z = fmaf(xv.z, s, bv.z);
    o.w = fmaf(xv.w, s, bv.w);
    reinterpret_cast<float4*>(agg)[t] = o;
}

// ---------------- edge scatter: agg[dst] += xw[src] * coef ----------------
// 16 threads per edge, one float4 (16B) each: 256B coalesced gather per edge.
__global__ void k_scatter(const int* __restrict__ src, const int* __restrict__ dst,
                          const float* __restrict__ coef, const float* __restrict__ xw,
                          float* __restrict__ agg, int E) {
    int t = blockIdx.x * blockDim.x + threadIdx.x;
    int e = t >> 4, c = t & 15;
    if (e >= E) return;
    int s = src[e], d = dst[e];
    float cf = coef[e];
    float4 xv = reinterpret_cast<const float4*>(xw + (size_t)s * NODE_D)[c];
    float* ap = agg + (size_t)d * NODE_D + c * 4;
    unsafeAtomicAdd(ap + 0, xv.x * cf);
    unsafeAtomicAdd(ap + 1, xv.y * cf);
    unsafeAtomicAdd(ap + 2, xv.z * cf);
    unsafeAtomicAdd(ap + 3, xv.w * cf);
}

// ---------------- log_softmax (wave per row, d=64) + relu -> next h ----------------
// NOTE: reference applies relu BEFORE log_softmax for layers 0-3.
__global__ void k_finish(const float* __restrict__ agg, float* __restrict__ out,
                         float* __restrict__ hnext, int n, int do_relu) {
    const int j   = threadIdx.x & 63;
    const int row = blockIdx.x * 4 + (threadIdx.x >> 6);
    if (row >= n) return;
    float v = agg[(size_t)row * NODE_D + j];
    if (do_relu) {
        v = fmaxf(v, 0.0f);
        hnext[(size_t)row * NODE_D + j] = v;
    }
    float m = v;
#pragma unroll
    for (int o = 32; o > 0; o >>= 1) m = fmaxf(m, __shfl_xor(m, o));
    float ex = __expf(v - m);
    float s = ex;
#pragma unroll
    for (int o = 32; o > 0; o >>= 1) s += __shfl_xor(s, o);
    out[(size_t)row * NODE_D + j] = v - m - __logf(s);
}

// ---------------- launch ----------------
extern "C" void kernel_launch(void* const* d_in, const int* in_sizes, int n_in,
                              void* d_out, int out_size, void* d_ws, size_t ws_size,
                              hipStream_t stream) {
    const float* x  = (const float*)d_in[0];
    const int*   ei = (const int*)d_in[1];
    const int n = in_sizes[0] / 128;       // x is [N,128]
    const int E = in_sizes[1] / 2;         // edge_index is [2,E]
    const int* src = ei;
    const int* dst = ei + E;

    const float* W[5];
    const float* b[5];
    for (int i = 0; i < 5; ++i) {
        W[i] = (const float*)d_in[2 + 2 * i];
        b[i] = (const float*)d_in[3 + 2 * i];
    }

    float* ws   = (float*)d_ws;
    float* dinv = ws;                                   // [n]
    float* coef = dinv + n;                             // [E]
    float* xw   = coef + E;                             // [n*64]
    float* agg  = xw + (size_t)n * NODE_D;              // [n*64]
    float* h    = agg + (size_t)n * NODE_D;             // [n*64]
    float* out  = (float*)d_out;                        // [5, n, 64]

    const int B = 256;

    // norm precompute
    k_init_deg<<<(n + B - 1) / B, B, 0, stream>>>(dinv, n);
    k_accum_deg<<<(E + B - 1) / B, B, 0, stream>>>(dst, dinv, E);
    k_dinv<<<(n + B - 1) / B, B, 0, stream>>>(dinv, n);
    k_coef<<<(E + B - 1) / B, B, 0, stream>>>(src, dst, dinv, coef, E);

    const float* hin = x;
    for (int i = 0; i < 5; ++i) {
        if (i == 0)
            k_gemm<128><<<(n + 3) / 4, B, 0, stream>>>(hin, W[i], xw, n);
        else
            k_gemm<64><<<(n + 3) / 4, B, 0, stream>>>(hin, W[i], xw, n);

        k_init_agg<<<((size_t)n * 16 + B - 1) / B, B, 0, stream>>>(xw, dinv, b[i], agg, n);
        k_scatter<<<((size_t)E * 16 + B - 1) / B, B, 0, stream>>>(src, dst, coef, xw, agg, E);
        k_finish<<<(n + 3) / 4, B, 0, stream>>>(agg, out + (size_t)i * n * NODE_D, h, n,
                                                (i < 4) ? 1 : 0);
        hin = h;
    }
}

// Round 3
// 1240.761 us; speedup vs baseline: 4.8931x; 4.8931x over previous
//
#include <hip/hip_runtime.h>
#include <math.h>

#define NODE_D 64

// ================= CSR build (once per call) =================

__global__ void k_hist(const int* __restrict__ dst, int* __restrict__ deg, int E) {
    int e = blockIdx.x * blockDim.x + threadIdx.x;
    if (e < E) atomicAdd(&deg[dst[e]], 1);
}

// block-level scan (1024 threads): per-element block-local EXCLUSIVE prefix + block total
__global__ void k_scan1(const int* __restrict__ deg, int* __restrict__ offs,
                        int* __restrict__ bsum, int n) {
    __shared__ int sm[1024];
    int tid = threadIdx.x;
    int i = blockIdx.x * 1024 + tid;
    int v = (i < n) ? deg[i] : 0;
    int val = v;
    sm[tid] = val;
    __syncthreads();
#pragma unroll
    for (int o = 1; o < 1024; o <<= 1) {
        int t = (tid >= o) ? sm[tid - o] : 0;
        __syncthreads();
        val += t;
        sm[tid] = val;
        __syncthreads();
    }
    if (i < n) offs[i] = val - v;            // block-local exclusive
    if (tid == 1023) bsum[blockIdx.x] = val; // block total
}

// exclusive scan of the (<=1024) block sums, in place
__global__ void k_scan2(int* __restrict__ bsum, int nb) {
    __shared__ int sm[1024];
    int tid = threadIdx.x;
    int v = (tid < nb) ? bsum[tid] : 0;
    int val = v;
    sm[tid] = val;
    __syncthreads();
#pragma unroll
    for (int o = 1; o < 1024; o <<= 1) {
        int t = (tid >= o) ? sm[tid - o] : 0;
        __syncthreads();
        val += t;
        sm[tid] = val;
        __syncthreads();
    }
    if (tid < nb) bsum[tid] = val - v;
}

// add block bases; produce cursor copy; offs[n]=E; dinv = rsqrt(deg+1)
__global__ void k_scan3(int* __restrict__ offs, const int* __restrict__ bsum,
                        int* __restrict__ cursor, const int* __restrict__ deg,
                        float* __restrict__ dinv, int n, int E) {
    int i = blockIdx.x * blockDim.x + threadIdx.x;
    if (i < n) {
        int o = offs[i] + bsum[i >> 10];
        offs[i] = o;
        cursor[i] = o;
        dinv[i] = rsqrtf((float)(deg[i] + 1));   // +1 = self-loop
    }
    if (i == 0) offs[n] = E;
}

__global__ void k_fill(const int* __restrict__ src, const int* __restrict__ dst,
                       int* __restrict__ cursor, int* __restrict__ csr, int E) {
    int e = blockIdx.x * blockDim.x + threadIdx.x;
    if (e < E) {
        int pos = atomicAdd(&cursor[dst[e]], 1);
        csr[pos] = src[e];
    }
}

// ================= dense y = dinv .* (h @ W) =================
template <int K>
__global__ void k_gemm(const float* __restrict__ h, const float* __restrict__ W,
                       const float* __restrict__ dinv, float* __restrict__ y, int n) {
    const int j   = threadIdx.x & 63;
    const int row = blockIdx.x * 4 + (threadIdx.x >> 6);
    if (row >= n) return;
    const float* hp = h + (size_t)row * K;
    float acc = 0.0f;
#pragma unroll
    for (int k = 0; k < K; k += 4) {
        float4 xv = *reinterpret_cast<const float4*>(hp + k);
        acc = fmaf(xv.x, W[(k + 0) * NODE_D + j], acc);
        acc = fmaf(xv.y, W[(k + 1) * NODE_D + j], acc);
        acc = fmaf(xv.z, W[(k + 2) * NODE_D + j], acc);
        acc = fmaf(xv.w, W[(k + 3) * NODE_D + j], acc);
    }
    y[(size_t)row * NODE_D + j] = acc * dinv[row];
}

// ========= pull aggregation + bias + relu + log_softmax (wave per row) =========
__global__ void k_aggfin(const int* __restrict__ offs, const int* __restrict__ csr,
                         const float* __restrict__ y, const float* __restrict__ dinv,
                         const float* __restrict__ b, float* __restrict__ out,
                         float* __restrict__ hnext, int n, int do_relu) {
    const int j   = threadIdx.x & 63;
    const int row = blockIdx.x * 4 + (threadIdx.x >> 6);
    if (row >= n) return;
    const int beg = offs[row], end = offs[row + 1];
    float acc = y[(size_t)row * NODE_D + j];   // self-loop term
    int e = beg;
    for (; e + 3 < end; e += 4) {
        int s0 = csr[e], s1 = csr[e + 1], s2 = csr[e + 2], s3 = csr[e + 3];
        float v0 = y[(size_t)s0 * NODE_D + j];
        float v1 = y[(size_t)s1 * NODE_D + j];
        float v2 = y[(size_t)s2 * NODE_D + j];
        float v3 = y[(size_t)s3 * NODE_D + j];
        acc += v0 + v1 + v2 + v3;
    }
    for (; e < end; ++e) acc += y[(size_t)csr[e] * NODE_D + j];

    float v = fmaf(dinv[row], acc, b[j]);
    if (do_relu) {
        v = fmaxf(v, 0.0f);
        hnext[(size_t)row * NODE_D + j] = v;
    }
    float m = v;
#pragma unroll
    for (int o = 32; o > 0; o >>= 1) m = fmaxf(m, __shfl_xor(m, o));
    float ex = __expf(v - m);
    float s = ex;
#pragma unroll
    for (int o = 32; o > 0; o >>= 1) s += __shfl_xor(s, o);
    out[(size_t)row * NODE_D + j] = v - m - __logf(s);
}

// ================= launch =================
extern "C" void kernel_launch(void* const* d_in, const int* in_sizes, int n_in,
                              void* d_out, int out_size, void* d_ws, size_t ws_size,
                              hipStream_t stream) {
    const float* x  = (const float*)d_in[0];
    const int*   ei = (const int*)d_in[1];
    const int n = in_sizes[0] / 128;       // x is [N,128]
    const int E = in_sizes[1] / 2;         // edge_index is [2,E]
    const int* src = ei;
    const int* dst = ei + E;

    const float* W[5];
    const float* b[5];
    for (int i = 0; i < 5; ++i) {
        W[i] = (const float*)d_in[2 + 2 * i];
        b[i] = (const float*)d_in[3 + 2 * i];
    }

    // workspace layout (all 4-byte elems; region sizes multiples of 4 elems)
    char* wsp = (char*)d_ws;
    int*   deg    = (int*)wsp;   wsp += (size_t)n * 4;
    int*   offs   = (int*)wsp;   wsp += (size_t)(n + 4) * 4;
    int*   bsum   = (int*)wsp;   wsp += (size_t)1024 * 4;
    int*   cursor = (int*)wsp;   wsp += (size_t)n * 4;
    int*   csr    = (int*)wsp;   wsp += (size_t)E * 4;
    float* dinv   = (float*)wsp; wsp += (size_t)n * 4;
    float* y      = (float*)wsp; wsp += (size_t)n * NODE_D * 4;
    float* h      = (float*)wsp;
    float* out    = (float*)d_out;          // [5, n, 64]

    const int B = 256;
    const int nb = (n + 1023) / 1024;

    // ---- CSR build ----
    hipMemsetAsync(deg, 0, (size_t)n * 4, stream);
    k_hist <<<(E + B - 1) / B, B, 0, stream>>>(dst, deg, E);
    k_scan1<<<nb, 1024, 0, stream>>>(deg, offs, bsum, n);
    k_scan2<<<1, 1024, 0, stream>>>(bsum, nb);
    k_scan3<<<(n + B - 1) / B, B, 0, stream>>>(offs, bsum, cursor, deg, dinv, n, E);
    k_fill <<<(E + B - 1) / B, B, 0, stream>>>(src, dst, cursor, csr, E);

    // ---- layers ----
    const float* hin = x;
    for (int i = 0; i < 5; ++i) {
        if (i == 0)
            k_gemm<128><<<(n + 3) / 4, B, 0, stream>>>(hin, W[i], dinv, y, n);
        else
            k_gemm<64><<<(n + 3) / 4, B, 0, stream>>>(hin, W[i], dinv, y, n);
        k_aggfin<<<(n + 3) / 4, B, 0, stream>>>(offs, csr, y, dinv, b[i],
                                                out + (size_t)i * n * NODE_D, h, n,
                                                (i < 4) ? 1 : 0);
        hin = h;
    }
}

// Round 4
// 1012.960 us; speedup vs baseline: 5.9935x; 1.2249x over previous
//
#include <hip/hip_runtime.h>
#include <math.h>

#define NODE_D 64

// ================= CSR build (once per call) =================

__global__ void k_hist(const int* __restrict__ dst, int* __restrict__ deg, int E) {
    int e = blockIdx.x * blockDim.x + threadIdx.x;
    if (e < E) atomicAdd(&deg[dst[e]], 1);
}

// block-level scan (1024 threads): per-element block-local EXCLUSIVE prefix + block total
__global__ void k_scan1(const int* __restrict__ deg, int* __restrict__ offs,
                        int* __restrict__ bsum, int n) {
    __shared__ int sm[1024];
    int tid = threadIdx.x;
    int i = blockIdx.x * 1024 + tid;
    int v = (i < n) ? deg[i] : 0;
    int val = v;
    sm[tid] = val;
    __syncthreads();
#pragma unroll
    for (int o = 1; o < 1024; o <<= 1) {
        int t = (tid >= o) ? sm[tid - o] : 0;
        __syncthreads();
        val += t;
        sm[tid] = val;
        __syncthreads();
    }
    if (i < n) offs[i] = val - v;            // block-local exclusive
    if (tid == 1023) bsum[blockIdx.x] = val; // block total
}

// exclusive scan of the (<=1024) block sums, in place
__global__ void k_scan2(int* __restrict__ bsum, int nb) {
    __shared__ int sm[1024];
    int tid = threadIdx.x;
    int v = (tid < nb) ? bsum[tid] : 0;
    int val = v;
    sm[tid] = val;
    __syncthreads();
#pragma unroll
    for (int o = 1; o < 1024; o <<= 1) {
        int t = (tid >= o) ? sm[tid - o] : 0;
        __syncthreads();
        val += t;
        sm[tid] = val;
        __syncthreads();
    }
    if (tid < nb) bsum[tid] = val - v;
}

// add block bases; produce cursor copy; offs[n]=E; dinv = rsqrt(deg+1)
__global__ void k_scan3(int* __restrict__ offs, const int* __restrict__ bsum,
                        int* __restrict__ cursor, const int* __restrict__ deg,
                        float* __restrict__ dinv, int n, int E) {
    int i = blockIdx.x * blockDim.x + threadIdx.x;
    if (i < n) {
        int o = offs[i] + bsum[i >> 10];
        offs[i] = o;
        cursor[i] = o;
        dinv[i] = rsqrtf((float)(deg[i] + 1));   // +1 = self-loop
    }
    if (i == 0) offs[n] = E;
}

__global__ void k_fill(const int* __restrict__ src, const int* __restrict__ dst,
                       int* __restrict__ cursor, int* __restrict__ csr, int E) {
    int e = blockIdx.x * blockDim.x + threadIdx.x;
    if (e < E) {
        int pos = atomicAdd(&cursor[dst[e]], 1);
        csr[pos] = src[e];
    }
}

// ================= dense y = dinv .* (h @ W) =================
// Block = 256 threads covers ROWS=32 rows. W staged in LDS once per block
// (lds[k][j]: lane j -> bank j%32, 2-way = free). Thread (g=tid>>6, j=tid&63)
// accumulates 8 rows x col j -> 8 independent FMA chains (ILP), h loads are
// wave-uniform float4 broadcasts.
template <int K>
__global__ __launch_bounds__(256) void k_gemm(const float* __restrict__ h,
                                              const float* __restrict__ W,
                                              const float* __restrict__ dinv,
                                              float* __restrict__ y, int n) {
    __shared__ float Wl[K * NODE_D];
    const int tid = threadIdx.x;
#pragma unroll
    for (int i = tid * 4; i < K * NODE_D; i += 256 * 4)
        *reinterpret_cast<float4*>(&Wl[i]) = *reinterpret_cast<const float4*>(&W[i]);
    __syncthreads();

    const int j = tid & 63;
    const int g = tid >> 6;
    const int row0 = blockIdx.x * 32 + g * 8;
    if (row0 >= n) return;                       // whole 64-lane group uniform
    const int nr = (n - row0 >= 8) ? 8 : (n - row0);

    float acc[8] = {0, 0, 0, 0, 0, 0, 0, 0};
    const float* hp = h + (size_t)row0 * K;

    if (nr == 8) {
        for (int k = 0; k < K; k += 4) {
            float w0 = Wl[(k + 0) * NODE_D + j];
            float w1 = Wl[(k + 1) * NODE_D + j];
            float w2 = Wl[(k + 2) * NODE_D + j];
            float w3 = Wl[(k + 3) * NODE_D + j];
#pragma unroll
            for (int r = 0; r < 8; ++r) {
                float4 hv = *reinterpret_cast<const float4*>(hp + (size_t)r * K + k);
                acc[r] = fmaf(hv.x, w0, acc[r]);
                acc[r] = fmaf(hv.y, w1, acc[r]);
                acc[r] = fmaf(hv.z, w2, acc[r]);
                acc[r] = fmaf(hv.w, w3, acc[r]);
            }
        }
#pragma unroll
        for (int r = 0; r < 8; ++r)
            y[(size_t)(row0 + r) * NODE_D + j] = acc[r] * dinv[row0 + r];
    } else {
        for (int k = 0; k < K; k += 4) {
            float w0 = Wl[(k + 0) * NODE_D + j];
            float w1 = Wl[(k + 1) * NODE_D + j];
            float w2 = Wl[(k + 2) * NODE_D + j];
            float w3 = Wl[(k + 3) * NODE_D + j];
            for (int r = 0; r < nr; ++r) {
                float4 hv = *reinterpret_cast<const float4*>(hp + (size_t)r * K + k);
                acc[r] = fmaf(hv.x, w0, acc[r]);
                acc[r] = fmaf(hv.y, w1, acc[r]);
                acc[r] = fmaf(hv.z, w2, acc[r]);
                acc[r] = fmaf(hv.w, w3, acc[r]);
            }
        }
        for (int r = 0; r < nr; ++r)
            y[(size_t)(row0 + r) * NODE_D + j] = acc[r] * dinv[row0 + r];
    }
}

// ========= pull aggregation + bias + relu + log_softmax (wave per row) =========
__global__ void k_aggfin(const int* __restrict__ offs, const int* __restrict__ csr,
                         const float* __restrict__ y, const float* __restrict__ dinv,
                         const float* __restrict__ b, float* __restrict__ out,
                         float* __restrict__ hnext, int n, int do_relu) {
    const int j   = threadIdx.x & 63;
    const int row = blockIdx.x * 4 + (threadIdx.x >> 6);
    if (row >= n) return;
    const int beg = offs[row], end = offs[row + 1];
    float acc = y[(size_t)row * NODE_D + j];   // self-loop term
    int e = beg;
    for (; e + 3 < end; e += 4) {
        int s0 = csr[e], s1 = csr[e + 1], s2 = csr[e + 2], s3 = csr[e + 3];
        float v0 = y[(size_t)s0 * NODE_D + j];
        float v1 = y[(size_t)s1 * NODE_D + j];
        float v2 = y[(size_t)s2 * NODE_D + j];
        float v3 = y[(size_t)s3 * NODE_D + j];
        acc += v0 + v1 + v2 + v3;
    }
    for (; e < end; ++e) acc += y[(size_t)csr[e] * NODE_D + j];

    float v = fmaf(dinv[row], acc, b[j]);
    if (do_relu) {
        v = fmaxf(v, 0.0f);
        hnext[(size_t)row * NODE_D + j] = v;
    }
    float m = v;
#pragma unroll
    for (int o = 32; o > 0; o >>= 1) m = fmaxf(m, __shfl_xor(m, o));
    float ex = __expf(v - m);
    float s = ex;
#pragma unroll
    for (int o = 32; o > 0; o >>= 1) s += __shfl_xor(s, o);
    out[(size_t)row * NODE_D + j] = v - m - __logf(s);
}

// ================= launch =================
extern "C" void kernel_launch(void* const* d_in, const int* in_sizes, int n_in,
                              void* d_out, int out_size, void* d_ws, size_t ws_size,
                              hipStream_t stream) {
    const float* x  = (const float*)d_in[0];
    const int*   ei = (const int*)d_in[1];
    const int n = in_sizes[0] / 128;       // x is [N,128]
    const int E = in_sizes[1] / 2;         // edge_index is [2,E]
    const int* src = ei;
    const int* dst = ei + E;

    const float* W[5];
    const float* b[5];
    for (int i = 0; i < 5; ++i) {
        W[i] = (const float*)d_in[2 + 2 * i];
        b[i] = (const float*)d_in[3 + 2 * i];
    }

    // workspace layout
    char* wsp = (char*)d_ws;
    int*   deg    = (int*)wsp;   wsp += (size_t)n * 4;
    int*   offs   = (int*)wsp;   wsp += (size_t)(n + 4) * 4;
    int*   bsum   = (int*)wsp;   wsp += (size_t)1024 * 4;
    int*   cursor = (int*)wsp;   wsp += (size_t)n * 4;
    int*   csr    = (int*)wsp;   wsp += (size_t)E * 4;
    float* dinv   = (float*)wsp; wsp += (size_t)n * 4;
    float* y      = (float*)wsp; wsp += (size_t)n * NODE_D * 4;
    float* h      = (float*)wsp;
    float* out    = (float*)d_out;          // [5, n, 64]

    const int B = 256;
    const int nb = (n + 1023) / 1024;

    // ---- CSR build ----
    hipMemsetAsync(deg, 0, (size_t)n * 4, stream);
    k_hist <<<(E + B - 1) / B, B, 0, stream>>>(dst, deg, E);
    k_scan1<<<nb, 1024, 0, stream>>>(deg, offs, bsum, n);
    k_scan2<<<1, 1024, 0, stream>>>(bsum, nb);
    k_scan3<<<(n + B - 1) / B, B, 0, stream>>>(offs, bsum, cursor, deg, dinv, n, E);
    k_fill <<<(E + B - 1) / B, B, 0, stream>>>(src, dst, cursor, csr, E);

    // ---- layers ----
    const float* hin = x;
    const int gemmGrid = (n + 31) / 32;
    for (int i = 0; i < 5; ++i) {
        if (i == 0)
            k_gemm<128><<<gemmGrid, B, 0, stream>>>(hin, W[i], dinv, y, n);
        else
            k_gemm<64><<<gemmGrid, B, 0, stream>>>(hin, W[i], dinv, y, n);
        k_aggfin<<<(n + 3) / 4, B, 0, stream>>>(offs, csr, y, dinv, b[i],
                                                out + (size_t)i * n * NODE_D, h, n,
                                                (i < 4) ? 1 : 0);
        hin = h;
    }
}

// Round 7
// 778.308 us; speedup vs baseline: 7.8004x; 1.3015x over previous
//
#include <hip/hip_runtime.h>
#include <math.h>

#define NODE_D 64

typedef short s8v  __attribute__((ext_vector_type(8)));   // 8 bf16 (4 VGPRs)
typedef float f4v  __attribute__((ext_vector_type(4)));   // MFMA accumulator

__device__ inline unsigned short f2b(float f) {           // f32 -> bf16 bits, RTNE
    unsigned int u = __float_as_uint(f);
    return (unsigned short)((u + 0x7FFFu + ((u >> 16) & 1u)) >> 16);
}

// ================= CSR build (once per call) =================

__global__ void k_hist(const int* __restrict__ dst, int* __restrict__ deg, int E) {
    int e = blockIdx.x * blockDim.x + threadIdx.x;
    if (e < E) atomicAdd(&deg[dst[e]], 1);
}

__global__ void k_scan1(const int* __restrict__ deg, int* __restrict__ offs,
                        int* __restrict__ bsum, int n) {
    __shared__ int sm[1024];
    int tid = threadIdx.x;
    int i = blockIdx.x * 1024 + tid;
    int v = (i < n) ? deg[i] : 0;
    int val = v;
    sm[tid] = val;
    __syncthreads();
#pragma unroll
    for (int o = 1; o < 1024; o <<= 1) {
        int t = (tid >= o) ? sm[tid - o] : 0;
        __syncthreads();
        val += t;
        sm[tid] = val;
        __syncthreads();
    }
    if (i < n) offs[i] = val - v;            // block-local exclusive
    if (tid == 1023) bsum[blockIdx.x] = val; // block total
}

__global__ void k_scan2(int* __restrict__ bsum, int nb) {
    __shared__ int sm[1024];
    int tid = threadIdx.x;
    int v = (tid < nb) ? bsum[tid] : 0;
    int val = v;
    sm[tid] = val;
    __syncthreads();
#pragma unroll
    for (int o = 1; o < 1024; o <<= 1) {
        int t = (tid >= o) ? sm[tid - o] : 0;
        __syncthreads();
        val += t;
        sm[tid] = val;
        __syncthreads();
    }
    if (tid < nb) bsum[tid] = val - v;
}

__global__ void k_scan3(int* __restrict__ offs, const int* __restrict__ bsum,
                        int* __restrict__ cursor, const int* __restrict__ deg,
                        float* __restrict__ dinv, int n, int E) {
    int i = blockIdx.x * blockDim.x + threadIdx.x;
    if (i < n) {
        int o = offs[i] + bsum[i >> 10];
        offs[i] = o;
        cursor[i] = o;
        dinv[i] = rsqrtf((float)(deg[i] + 1));   // +1 = self-loop
    }
    if (i == 0) offs[n] = E;
}

__global__ void k_fill(const int* __restrict__ src, const int* __restrict__ dst,
                       int* __restrict__ cursor, int* __restrict__ csr, int E) {
    int e = blockIdx.x * blockDim.x + threadIdx.x;
    if (e < E) {
        int pos = atomicAdd(&cursor[dst[e]], 1);
        csr[pos] = src[e];
    }
}

// ================= conversions / packing =================

// x f32 -> bf16, 4 elems/thread
__global__ void k_x2b(const float* __restrict__ x, unsigned short* __restrict__ xb, int n4) {
    int t = blockIdx.x * blockDim.x + threadIdx.x;
    if (t >= n4) return;
    float4 v = reinterpret_cast<const float4*>(x)[t];
    ushort4 o;
    o.x = f2b(v.x); o.y = f2b(v.y); o.z = f2b(v.z); o.w = f2b(v.w);
    reinterpret_cast<ushort4*>(xb)[t] = o;
}

// Pack W [K][64] f32 into MFMA B-fragment order (bf16):
// Wp[((s*4+t)*64 + l)*8 + i] = W[(s*32 + (l>>4)*8 + i)*64 + t*16 + (l&15)]
__global__ void k_wpack(const float* __restrict__ W, unsigned short* __restrict__ Wp, int total) {
    int p = blockIdx.x * blockDim.x + threadIdx.x;
    if (p >= total) return;
    int i = p & 7;
    int l = (p >> 3) & 63;
    int t = (p >> 9) & 3;
    int s = p >> 11;
    int k = s * 32 + ((l >> 4) << 3) + i;
    int c = t * 16 + (l & 15);
    Wp[p] = f2b(W[k * NODE_D + c]);
}

// ================= MFMA GEMM: y = dinv .* (A @ W) =================
// Block = 256 (4 waves); wave w: rows [blk*64 + w*16, +16), all 64 cols.
// A is bf16 [NPAD][K] row-major (padded rows garbage, stores guarded).
// A-frag: lane l holds A[row0+(l&15)][s*32 + (l>>4)*8 + i] -> one 16B load.
// C/D layout (m89-verified): col = l&15, row = row0 + (l>>4)*4 + reg.
template <int K>
__global__ __launch_bounds__(256) void k_mfma(const unsigned short* __restrict__ A,
                                              const unsigned short* __restrict__ Wp,
                                              const float* __restrict__ dinv,
                                              float* __restrict__ y, int n) {
    const int l = threadIdx.x & 63;
    const int w = threadIdx.x >> 6;
    const int row0 = blockIdx.x * 64 + w * 16;
    f4v c0 = {0, 0, 0, 0}, c1 = {0, 0, 0, 0}, c2 = {0, 0, 0, 0}, c3 = {0, 0, 0, 0};
    const short* ap = (const short*)A + (size_t)(row0 + (l & 15)) * K + ((l >> 4) << 3);
    const short* wp = (const short*)Wp + l * 8;
#pragma unroll
    for (int s = 0; s < K / 32; ++s) {
        s8v a  = *(const s8v*)(ap + s * 32);
        s8v b0 = *(const s8v*)(wp + (s * 4 + 0) * 512);
        s8v b1 = *(const s8v*)(wp + (s * 4 + 1) * 512);
        s8v b2 = *(const s8v*)(wp + (s * 4 + 2) * 512);
        s8v b3 = *(const s8v*)(wp + (s * 4 + 3) * 512);
        c0 = __builtin_amdgcn_mfma_f32_16x16x32_bf16(a, b0, c0, 0, 0, 0);
        c1 = __builtin_amdgcn_mfma_f32_16x16x32_bf16(a, b1, c1, 0, 0, 0);
        c2 = __builtin_amdgcn_mfma_f32_16x16x32_bf16(a, b2, c2, 0, 0, 0);
        c3 = __builtin_amdgcn_mfma_f32_16x16x32_bf16(a, b3, c3, 0, 0, 0);
    }
    const int rbase = row0 + ((l >> 4) << 2);
    const int cbase = l & 15;
#pragma unroll
    for (int i = 0; i < 4; ++i) {
        int r = rbase + i;
        if (r < n) {
            float dv = dinv[r];
            y[(size_t)r * NODE_D + cbase     ] = c0[i] * dv;
            y[(size_t)r * NODE_D + cbase + 16] = c1[i] * dv;
            y[(size_t)r * NODE_D + cbase + 32] = c2[i] * dv;
            y[(size_t)r * NODE_D + cbase + 48] = c3[i] * dv;
        }
    }
}

// ========= pull aggregation + bias + relu + log_softmax (wave per row) =========
__global__ void k_aggfin(const int* __restrict__ offs, const int* __restrict__ csr,
                         const float* __restrict__ y, const float* __restrict__ dinv,
                         const float* __restrict__ b, float* __restrict__ out,
                         unsigned short* __restrict__ hnext, int n, int do_relu) {
    const int j   = threadIdx.x & 63;
    const int row = blockIdx.x * 4 + (threadIdx.x >> 6);
    if (row >= n) return;
    const int beg = offs[row], end = offs[row + 1];
    float acc = y[(size_t)row * NODE_D + j];   // self-loop term
    int e = beg;
    for (; e + 3 < end; e += 4) {
        int s0 = csr[e], s1 = csr[e + 1], s2 = csr[e + 2], s3 = csr[e + 3];
        float v0 = y[(size_t)s0 * NODE_D + j];
        float v1 = y[(size_t)s1 * NODE_D + j];
        float v2 = y[(size_t)s2 * NODE_D + j];
        float v3 = y[(size_t)s3 * NODE_D + j];
        acc += v0 + v1 + v2 + v3;
    }
    for (; e < end; ++e) acc += y[(size_t)csr[e] * NODE_D + j];

    float v = fmaf(dinv[row], acc, b[j]);
    if (do_relu) {
        v = fmaxf(v, 0.0f);
        hnext[(size_t)row * NODE_D + j] = f2b(v);
    }
    float m = v;
#pragma unroll
    for (int o = 32; o > 0; o >>= 1) m = fmaxf(m, __shfl_xor(m, o));
    float ex = __expf(v - m);
    float s = ex;
#pragma unroll
    for (int o = 32; o > 0; o >>= 1) s += __shfl_xor(s, o);
    out[(size_t)row * NODE_D + j] = v - m - __logf(s);
}

// ================= launch =================
extern "C" void kernel_launch(void* const* d_in, const int* in_sizes, int n_in,
                              void* d_out, int out_size, void* d_ws, size_t ws_size,
                              hipStream_t stream) {
    const float* x  = (const float*)d_in[0];
    const int*   ei = (const int*)d_in[1];
    const int n = in_sizes[0] / 128;       // x is [N,128]
    const int E = in_sizes[1] / 2;         // edge_index is [2,E]
    const int* src = ei;
    const int* dst = ei + E;

    const float* W[5];
    const float* b[5];
    for (int i = 0; i < 5; ++i) {
        W[i] = (const float*)d_in[2 + 2 * i];
        b[i] = (const float*)d_in[3 + 2 * i];
    }

    const int NPAD = ((n + 63) / 64) * 64;   // pad rows for unguarded A-frag loads

    // workspace layout
    char* wsp = (char*)d_ws;
    int*            deg    = (int*)wsp;            wsp += (size_t)n * 4;
    int*            offs   = (int*)wsp;            wsp += (size_t)(n + 4) * 4;
    int*            bsum   = (int*)wsp;            wsp += (size_t)1024 * 4;
    int*            cursor = (int*)wsp;            wsp += (size_t)n * 4;
    int*            csr    = (int*)wsp;            wsp += (size_t)E * 4;
    float*          dinv   = (float*)wsp;          wsp += (size_t)n * 4;
    float*          y      = (float*)wsp;          wsp += (size_t)n * NODE_D * 4;
    unsigned short* xb     = (unsigned short*)wsp; wsp += (size_t)NPAD * 128 * 2;
    unsigned short* hb     = (unsigned short*)wsp; wsp += (size_t)NPAD * NODE_D * 2;
    unsigned short* wpck   = (unsigned short*)wsp; // 128*64 + 4*64*64 = 24576 bf16
    float*          out    = (float*)d_out;        // [5, n, 64]

    unsigned short* wp[5];
    wp[0] = wpck;
    for (int i = 1; i < 5; ++i) wp[i] = wpck + 128 * 64 + (size_t)(i - 1) * 64 * 64;

    const int B = 256;
    const int nb = (n + 1023) / 1024;

    // ---- CSR build ----
    hipMemsetAsync(deg, 0, (size_t)n * 4, stream);
    k_hist <<<(E + B - 1) / B, B, 0, stream>>>(dst, deg, E);
    k_scan1<<<nb, 1024, 0, stream>>>(deg, offs, bsum, n);
    k_scan2<<<1, 1024, 0, stream>>>(bsum, nb);
    k_scan3<<<(n + B - 1) / B, B, 0, stream>>>(offs, bsum, cursor, deg, dinv, n, E);
    k_fill <<<(E + B - 1) / B, B, 0, stream>>>(src, dst, cursor, csr, E);

    // ---- conversions / weight packing ----
    k_x2b<<<((n * 32) + B - 1) / B, B, 0, stream>>>(x, xb, n * 32);   // n*128/4 threads
    for (int i = 0; i < 5; ++i) {
        int total = (i == 0 ? 128 : 64) * NODE_D;
        k_wpack<<<(total + B - 1) / B, B, 0, stream>>>(W[i], wp[i], total);
    }

    // ---- layers ----
    const int gemmGrid = (n + 63) / 64;
    for (int i = 0; i < 5; ++i) {
        if (i == 0)
            k_mfma<128><<<gemmGrid, B, 0, stream>>>(xb, wp[i], dinv, y, n);
        else
            k_mfma<64><<<gemmGrid, B, 0, stream>>>(hb, wp[i], dinv, y, n);
        k_aggfin<<<(n + 3) / 4, B, 0, stream>>>(offs, csr, y, dinv, b[i],
                                                out + (size_t)i * n * NODE_D, hb, n,
                                                (i < 4) ? 1 : 0);
    }
}

// Round 8
// 751.624 us; speedup vs baseline: 8.0774x; 1.0355x over previous
//
#include <hip/hip_runtime.h>
#include <math.h>

#define NODE_D 64

typedef short s8v  __attribute__((ext_vector_type(8)));   // 8 bf16 (4 VGPRs)
typedef float f4v  __attribute__((ext_vector_type(4)));   // MFMA accumulator

__device__ inline unsigned short f2b(float f) {           // f32 -> bf16 bits, RTNE
    unsigned int u = __float_as_uint(f);
    return (unsigned short)((u + 0x7FFFu + ((u >> 16) & 1u)) >> 16);
}
__device__ inline float b2f(unsigned short u) {           // bf16 bits -> f32
    return __uint_as_float((unsigned int)u << 16);
}

// ================= CSR build (once per call) =================

__global__ void k_hist(const int* __restrict__ dst, int* __restrict__ deg, int E) {
    int e = blockIdx.x * blockDim.x + threadIdx.x;
    if (e < E) atomicAdd(&deg[dst[e]], 1);
}

__global__ void k_scan1(const int* __restrict__ deg, int* __restrict__ offs,
                        int* __restrict__ bsum, int n) {
    __shared__ int sm[1024];
    int tid = threadIdx.x;
    int i = blockIdx.x * 1024 + tid;
    int v = (i < n) ? deg[i] : 0;
    int val = v;
    sm[tid] = val;
    __syncthreads();
#pragma unroll
    for (int o = 1; o < 1024; o <<= 1) {
        int t = (tid >= o) ? sm[tid - o] : 0;
        __syncthreads();
        val += t;
        sm[tid] = val;
        __syncthreads();
    }
    if (i < n) offs[i] = val - v;            // block-local exclusive
    if (tid == 1023) bsum[blockIdx.x] = val; // block total
}

__global__ void k_scan2(int* __restrict__ bsum, int nb) {
    __shared__ int sm[1024];
    int tid = threadIdx.x;
    int v = (tid < nb) ? bsum[tid] : 0;
    int val = v;
    sm[tid] = val;
    __syncthreads();
#pragma unroll
    for (int o = 1; o < 1024; o <<= 1) {
        int t = (tid >= o) ? sm[tid - o] : 0;
        __syncthreads();
        val += t;
        sm[tid] = val;
        __syncthreads();
    }
    if (tid < nb) bsum[tid] = val - v;
}

__global__ void k_scan3(int* __restrict__ offs, const int* __restrict__ bsum,
                        int* __restrict__ cursor, const int* __restrict__ deg,
                        float* __restrict__ dinv, int n, int E) {
    int i = blockIdx.x * blockDim.x + threadIdx.x;
    if (i < n) {
        int o = offs[i] + bsum[i >> 10];
        offs[i] = o;
        cursor[i] = o;
        dinv[i] = rsqrtf((float)(deg[i] + 1));   // +1 = self-loop
    }
    if (i == 0) offs[n] = E;
}

__global__ void k_fill(const int* __restrict__ src, const int* __restrict__ dst,
                       int* __restrict__ cursor, int* __restrict__ csr, int E) {
    int e = blockIdx.x * blockDim.x + threadIdx.x;
    if (e < E) {
        int pos = atomicAdd(&cursor[dst[e]], 1);
        csr[pos] = src[e];
    }
}

// ================= conversions / packing =================

// x f32 -> bf16, 4 elems/thread
__global__ void k_x2b(const float* __restrict__ x, unsigned short* __restrict__ xb, int n4) {
    int t = blockIdx.x * blockDim.x + threadIdx.x;
    if (t >= n4) return;
    float4 v = reinterpret_cast<const float4*>(x)[t];
    ushort4 o;
    o.x = f2b(v.x); o.y = f2b(v.y); o.z = f2b(v.z); o.w = f2b(v.w);
    reinterpret_cast<ushort4*>(xb)[t] = o;
}

// Pack W [K][64] f32 into MFMA B-fragment order (bf16):
// Wp[((s*4+t)*64 + l)*8 + i] = W[(s*32 + (l>>4)*8 + i)*64 + t*16 + (l&15)]
__global__ void k_wpack(const float* __restrict__ W, unsigned short* __restrict__ Wp, int total) {
    int p = blockIdx.x * blockDim.x + threadIdx.x;
    if (p >= total) return;
    int i = p & 7;
    int l = (p >> 3) & 63;
    int t = (p >> 9) & 3;
    int s = p >> 11;
    int k = s * 32 + ((l >> 4) << 3) + i;
    int c = t * 16 + (l & 15);
    Wp[p] = f2b(W[k * NODE_D + c]);
}

// ================= MFMA GEMM: y(bf16) = dinv .* (A @ W) =================
// Block = 256 (4 waves); wave w: rows [blk*64 + w*16, +16), all 64 cols.
// C/D layout (m89-verified): col = l&15, row = row0 + (l>>4)*4 + reg.
template <int K>
__global__ __launch_bounds__(256) void k_mfma(const unsigned short* __restrict__ A,
                                              const unsigned short* __restrict__ Wp,
                                              const float* __restrict__ dinv,
                                              unsigned short* __restrict__ y, int n) {
    const int l = threadIdx.x & 63;
    const int w = threadIdx.x >> 6;
    const int row0 = blockIdx.x * 64 + w * 16;
    f4v c0 = {0, 0, 0, 0}, c1 = {0, 0, 0, 0}, c2 = {0, 0, 0, 0}, c3 = {0, 0, 0, 0};
    const short* ap = (const short*)A + (size_t)(row0 + (l & 15)) * K + ((l >> 4) << 3);
    const short* wp = (const short*)Wp + l * 8;
#pragma unroll
    for (int s = 0; s < K / 32; ++s) {
        s8v a  = *(const s8v*)(ap + s * 32);
        s8v b0 = *(const s8v*)(wp + (s * 4 + 0) * 512);
        s8v b1 = *(const s8v*)(wp + (s * 4 + 1) * 512);
        s8v b2 = *(const s8v*)(wp + (s * 4 + 2) * 512);
        s8v b3 = *(const s8v*)(wp + (s * 4 + 3) * 512);
        c0 = __builtin_amdgcn_mfma_f32_16x16x32_bf16(a, b0, c0, 0, 0, 0);
        c1 = __builtin_amdgcn_mfma_f32_16x16x32_bf16(a, b1, c1, 0, 0, 0);
        c2 = __builtin_amdgcn_mfma_f32_16x16x32_bf16(a, b2, c2, 0, 0, 0);
        c3 = __builtin_amdgcn_mfma_f32_16x16x32_bf16(a, b3, c3, 0, 0, 0);
    }
    const int rbase = row0 + ((l >> 4) << 2);
    const int cbase = l & 15;
#pragma unroll
    for (int i = 0; i < 4; ++i) {
        int r = rbase + i;
        if (r < n) {
            float dv = dinv[r];
            unsigned short* yp = y + (size_t)r * NODE_D + cbase;
            yp[0]  = f2b(c0[i] * dv);
            yp[16] = f2b(c1[i] * dv);
            yp[32] = f2b(c2[i] * dv);
            yp[48] = f2b(c3[i] * dv);
        }
    }
}

// ========= pull aggregation + bias + relu + log_softmax (wave per row) =========
// y is bf16: per edge a wave gathers 128B (2 cache lines vs 4 for f32).
__global__ void k_aggfin(const int* __restrict__ offs, const int* __restrict__ csr,
                         const unsigned short* __restrict__ y, const float* __restrict__ dinv,
                         const float* __restrict__ b, float* __restrict__ out,
                         unsigned short* __restrict__ hnext, int n, int do_relu) {
    const int j   = threadIdx.x & 63;
    const int row = blockIdx.x * 4 + (threadIdx.x >> 6);
    if (row >= n) return;
    const int beg = offs[row], end = offs[row + 1];
    float acc = b2f(y[(size_t)row * NODE_D + j]);   // self-loop term
    int e = beg;
    for (; e + 7 < end; e += 8) {
        int s0 = csr[e],     s1 = csr[e + 1], s2 = csr[e + 2], s3 = csr[e + 3];
        int s4 = csr[e + 4], s5 = csr[e + 5], s6 = csr[e + 6], s7 = csr[e + 7];
        float v0 = b2f(y[(size_t)s0 * NODE_D + j]);
        float v1 = b2f(y[(size_t)s1 * NODE_D + j]);
        float v2 = b2f(y[(size_t)s2 * NODE_D + j]);
        float v3 = b2f(y[(size_t)s3 * NODE_D + j]);
        float v4 = b2f(y[(size_t)s4 * NODE_D + j]);
        float v5 = b2f(y[(size_t)s5 * NODE_D + j]);
        float v6 = b2f(y[(size_t)s6 * NODE_D + j]);
        float v7 = b2f(y[(size_t)s7 * NODE_D + j]);
        acc += ((v0 + v1) + (v2 + v3)) + ((v4 + v5) + (v6 + v7));
    }
    for (; e < end; ++e) acc += b2f(y[(size_t)csr[e] * NODE_D + j]);

    float v = fmaf(dinv[row], acc, b[j]);
    if (do_relu) {
        v = fmaxf(v, 0.0f);
        hnext[(size_t)row * NODE_D + j] = f2b(v);
    }
    float m = v;
#pragma unroll
    for (int o = 32; o > 0; o >>= 1) m = fmaxf(m, __shfl_xor(m, o));
    float ex = __expf(v - m);
    float s = ex;
#pragma unroll
    for (int o = 32; o > 0; o >>= 1) s += __shfl_xor(s, o);
    out[(size_t)row * NODE_D + j] = v - m - __logf(s);
}

// ================= launch =================
extern "C" void kernel_launch(void* const* d_in, const int* in_sizes, int n_in,
                              void* d_out, int out_size, void* d_ws, size_t ws_size,
                              hipStream_t stream) {
    const float* x  = (const float*)d_in[0];
    const int*   ei = (const int*)d_in[1];
    const int n = in_sizes[0] / 128;       // x is [N,128]
    const int E = in_sizes[1] / 2;         // edge_index is [2,E]
    const int* src = ei;
    const int* dst = ei + E;

    const float* W[5];
    const float* b[5];
    for (int i = 0; i < 5; ++i) {
        W[i] = (const float*)d_in[2 + 2 * i];
        b[i] = (const float*)d_in[3 + 2 * i];
    }

    const int NPAD = ((n + 63) / 64) * 64;   // pad rows for unguarded A-frag loads

    // workspace layout
    char* wsp = (char*)d_ws;
    int*            deg    = (int*)wsp;            wsp += (size_t)n * 4;
    int*            offs   = (int*)wsp;            wsp += (size_t)(n + 4) * 4;
    int*            bsum   = (int*)wsp;            wsp += (size_t)1024 * 4;
    int*            cursor = (int*)wsp;            wsp += (size_t)n * 4;
    int*            csr    = (int*)wsp;            wsp += (size_t)E * 4;
    float*          dinv   = (float*)wsp;          wsp += (size_t)n * 4;
    unsigned short* y      = (unsigned short*)wsp; wsp += (size_t)NPAD * NODE_D * 2;
    unsigned short* xb     = (unsigned short*)wsp; wsp += (size_t)NPAD * 128 * 2;
    unsigned short* hb     = (unsigned short*)wsp; wsp += (size_t)NPAD * NODE_D * 2;
    unsigned short* wpck   = (unsigned short*)wsp; // 128*64 + 4*64*64 = 24576 bf16
    float*          out    = (float*)d_out;        // [5, n, 64]

    unsigned short* wp[5];
    wp[0] = wpck;
    for (int i = 1; i < 5; ++i) wp[i] = wpck + 128 * 64 + (size_t)(i - 1) * 64 * 64;

    const int B = 256;
    const int nb = (n + 1023) / 1024;

    // ---- CSR build ----
    hipMemsetAsync(deg, 0, (size_t)n * 4, stream);
    k_hist <<<(E + B - 1) / B, B, 0, stream>>>(dst, deg, E);
    k_scan1<<<nb, 1024, 0, stream>>>(deg, offs, bsum, n);
    k_scan2<<<1, 1024, 0, stream>>>(bsum, nb);
    k_scan3<<<(n + B - 1) / B, B, 0, stream>>>(offs, bsum, cursor, deg, dinv, n, E);
    k_fill <<<(E + B - 1) / B, B, 0, stream>>>(src, dst, cursor, csr, E);

    // ---- conversions / weight packing ----
    k_x2b<<<((n * 32) + B - 1) / B, B, 0, stream>>>(x, xb, n * 32);   // n*128/4 threads
    for (int i = 0; i < 5; ++i) {
        int total = (i == 0 ? 128 : 64) * NODE_D;
        k_wpack<<<(total + B - 1) / B, B, 0, stream>>>(W[i], wp[i], total);
    }

    // ---- layers ----
    const int gemmGrid = (n + 63) / 64;
    for (int i = 0; i < 5; ++i) {
        if (i == 0)
            k_mfma<128><<<gemmGrid, B, 0, stream>>>(xb, wp[i], dinv, y, n);
        else
            k_mfma<64><<<gemmGrid, B, 0, stream>>>(hb, wp[i], dinv, y, n);
        k_aggfin<<<(n + 3) / 4, B, 0, stream>>>(offs, csr, y, dinv, b[i],
                                                out + (size_t)i * n * NODE_D, hb, n,
                                                (i < 4) ? 1 : 0);
    }
}